// Round 10
// baseline (506.271 us; speedup 1.0000x reference)
//
#include <hip/hip_runtime.h>

constexpr int NN = 100000;   // nodes
constexpr int NE = 1600000;  // edges
constexpr int NG = 5000;     // graphs
constexpr int BKT = 64;      // dst-nodes per bucket
constexpr int NBKT = (NN + BKT - 1) / BKT;   // 1563
constexpr int NB = 128;      // hist/scatter blocks
constexpr int CHUNK = NE / NB;               // 12500 exact

typedef float v2f __attribute__((ext_vector_type(2)));

// ---- workspace layout (4B words) ----
constexpr size_t OFF_G  = 0;                            // g      [NG*10]
constexpr size_t OFF_BH = 50048;                        // bh     [NB][NBKT]
constexpr size_t OFF_ST = OFF_BH + (size_t)NB * NBKT;   // starts [NBKT+1]
constexpr size_t OFF_PM = OFF_ST + NBKT + 1;            // perm (fallback only) [NE]
constexpr size_t OFF_SP = OFF_PM + NE;                  // srcp   [NE]
constexpr size_t OFF_EP = ((OFF_SP + NE) + 15) & ~(size_t)15;  // eattr_perm [NE*16]
constexpr size_t NEED_WORDS = OFF_EP + (size_t)NE * 16; // ~116 MB (fits, proven R8)
// R9 post-mortem: reorder+direct loads got k_edge to 134.8us/32% VALU, but
// 84 arch + 96 AGPR(W) = 180 regs -> 2 waves/SIMD regardless of (256,3);
// features still issued+consumed in-iteration -> ~700cyc exposed/iter.
// R10: (a) 1-deep feature prefetch (R2's idea, now viable: cap 256 via
// (256,2), ~215 regs, no spill) -> every load's consumer >=1 iter away;
// (b) fuse reorder into scatter (slot is already there; kills inv pass).

// ---------------- pass A: per-block bucket histogram (+ zero g) ----------------
__global__ __launch_bounds__(256) void k_hist(const int* __restrict__ ei,
                                              int* __restrict__ bh,
                                              float* __restrict__ g) {
  __shared__ int lh[NBKT];
  for (int i = threadIdx.x; i < NBKT; i += 256) lh[i] = 0;
  __syncthreads();
  const int* dstp = ei + NE;
  int s = blockIdx.x * CHUNK;
  for (int i = s + threadIdx.x; i < s + CHUNK; i += 256)
    atomicAdd(&lh[dstp[i] >> 6], 1);                    // LDS int atomic
  int gid = blockIdx.x * 256 + threadIdx.x;             // zero g: 12,500 float4
  if (gid < 12500) ((float4*)g)[gid] = make_float4(0.f, 0.f, 0.f, 0.f);
  __syncthreads();
  int* out = bh + (size_t)blockIdx.x * NBKT;            // block-major: coalesced
  for (int k = threadIdx.x; k < NBKT; k += 256) out[k] = lh[k];
}

// ---------------- pass B1: per-bucket totals (grid-parallel) ----------------
__global__ __launch_bounds__(256) void k_btot(const int* __restrict__ bh,
                                              int* __restrict__ starts) {
  int k = blockIdx.x * 256 + threadIdx.x;
  if (k >= NBKT) return;
  int tot = 0;
  for (int b = 0; b < NB; b += 4) {                     // coalesced: k-consecutive
    int a0 = bh[(size_t)(b    ) * NBKT + k];
    int a1 = bh[(size_t)(b + 1) * NBKT + k];
    int a2 = bh[(size_t)(b + 2) * NBKT + k];
    int a3 = bh[(size_t)(b + 3) * NBKT + k];
    tot += a0 + a1 + a2 + a3;
  }
  starts[k] = tot;
}

// ---------------- pass B2: exclusive scan of 1563 totals ----------------
__global__ __launch_bounds__(1024) void k_sscan(int* __restrict__ starts) {
  __shared__ int s0[1024], s1[1024];
  int t = threadIdx.x;
  int k0 = 2 * t, k1 = 2 * t + 1;
  int tot0 = (k0 < NBKT) ? starts[k0] : 0;
  int tot1 = (k1 < NBKT) ? starts[k1] : 0;
  int ssum = tot0 + tot1;
  int* cur = s0; int* nxt = s1;
  cur[t] = ssum;
  __syncthreads();
  for (int off = 1; off < 1024; off <<= 1) {            // Hillis-Steele inclusive
    int v = cur[t];
    if (t >= off) v += cur[t - off];
    nxt[t] = v;
    __syncthreads();
    int* tmp = cur; cur = nxt; nxt = tmp;
  }
  int excl = cur[t] - ssum;
  if (k0 < NBKT) starts[k0] = excl;
  if (k1 <= NBKT) starts[k1] = excl + tot0;             // t=781 writes starts[NBKT]=NE
}

// ---------------- pass B3: per-(block,bucket) bases (grid-parallel) ----------------
__global__ __launch_bounds__(256) void k_bases(int* __restrict__ bh,
                                               const int* __restrict__ starts) {
  int k = blockIdx.x * 256 + threadIdx.x;
  if (k >= NBKT) return;
  int run = starts[k];
  for (int b = 0; b < NB; ++b) {
    size_t idx = (size_t)b * NBKT + k;
    int v = bh[idx];
    bh[idx] = run;
    run += v;
  }
}

// ---------------- pass C: scatter + fused eattr/src reorder ----------------
// PRE: per edge i (original order, streaming reads), compute slot via LDS
// atomic, then write srcp[slot] = src|dl<<24 and copy the 64B eattr row to
// eattr_perm[slot] (scattered writes, fire-and-forget; R8 measured this
// write pattern at ~4 TB/s effective in k_reorder). Kills the inv pass.
template <bool PRE>
__global__ __launch_bounds__(256) void k_scatter(const int* __restrict__ ei,
                                                 const int* __restrict__ bh,
                                                 int* __restrict__ pm,
                                                 const float* __restrict__ eattr,
                                                 float* __restrict__ ep_,
                                                 int* __restrict__ srcp) {
  __shared__ int base[NBKT];
  __shared__ int cnt[NBKT];
  const int* row = bh + (size_t)blockIdx.x * NBKT;
  for (int k = threadIdx.x; k < NBKT; k += 256) { base[k] = row[k]; cnt[k] = 0; }
  __syncthreads();
  const int* dstp = ei + NE;
  int s = blockIdx.x * CHUNK;
  for (int i = s + threadIdx.x; i < s + CHUNK; i += 256) {
    int d = dstp[i];
    int k = d >> 6;
    int r = atomicAdd(&cnt[k], 1);                      // LDS atomic
    int slot = base[k] + r;
    if (PRE) {
      srcp[slot] = ei[i] | ((d & 63) << 24);
      const float4* src4 = (const float4*)eattr + (size_t)i * 4;
      float4 v0 = src4[0], v1 = src4[1], v2 = src4[2], v3 = src4[3];
      float4* dst4 = (float4*)ep_ + (size_t)slot * 4;
      dst4[0] = v0; dst4[1] = v1; dst4[2] = v2; dst4[3] = v3;
    } else {
      pm[slot] = i | ((d & 63) << 24);
    }
  }
}

// ---------------- pass D: edge MLP + fused node MLP + graph pooling ----------------
// Lane (ep,jp): ep = edge slot (6/wave), jp = output pair (10). 4 waves/block.
// PRE: eattr_perm/srcp streaming (affine), nattr[src] the single dependent
// hop. 1-deep feature prefetch: iter i issues iter-(i+1)'s 8 float4 loads
// (eattr affine addr; nattr addr from sp1 which arrived an iter earlier) ->
// no load's consumer in its issue iteration. ~215 regs under (256,2) cap 256
// (R2's spill trap avoided). Occupancy stays 2 waves/SIMD - the trade is
// latency-hiding via ILP, since W's 96 pinned regs preclude 3 waves (R9).
#define PK4(V, K0) \
  a0 = __builtin_elementwise_fma(v2f{(V).x, (V).x}, W[K0+0], a0); \
  a1 = __builtin_elementwise_fma(v2f{(V).y, (V).y}, W[K0+1], a1); \
  a2 = __builtin_elementwise_fma(v2f{(V).z, (V).z}, W[K0+2], a2); \
  a3 = __builtin_elementwise_fma(v2f{(V).w, (V).w}, W[K0+3], a3);

template <bool PRE>
__global__ __launch_bounds__(256, 2) void k_edge(
    const int* __restrict__ ei,
    const float* __restrict__ nattr,
    const float* __restrict__ eattr,        // PRE: eattr_perm ; else raw eattr
    const float* __restrict__ Wm,
    const float* __restrict__ bm,
    const int* __restrict__ batch,
    const float* __restrict__ W1,
    const float* __restrict__ b1,
    const int* __restrict__ pm,             // PRE: srcp ; else perm
    const int* __restrict__ starts,
    float* __restrict__ g) {
  __shared__ float xt[20 * 65];    // padded rows
  __shared__ float gb[64 * 10];    // graph partials for this bucket's span
  __shared__ float4 wt4[250];      // weight bounce: [jp][t] pairs for cols 2jp,2jp+1
  __shared__ float4 us4[64 * 5];   // dst rows, padded stride 5 (4 used)
  __shared__ int s_se[2];
  __shared__ int s_bmin;
  int tid = threadIdx.x;
  for (int i = tid; i < 20 * 65; i += 256) xt[i] = 0.f;
  for (int i = tid; i < 640; i += 256) gb[i] = 0.f;
  if (tid < 240) {
    int j = tid / 24, t = tid - j * 24, k = 2 * t;
    wt4[j * 25 + t] = make_float4(Wm[k * 20 + 2 * j],       Wm[k * 20 + 2 * j + 1],
                                  Wm[(k + 1) * 20 + 2 * j], Wm[(k + 1) * 20 + 2 * j + 1]);
  }
  int nbase = blockIdx.x * BKT;
  {                                // stage the block's 64 dst rows (once)
    int dl = tid >> 2, part = tid & 3;
    int row = min(nbase + dl, NN - 1);
    us4[dl * 5 + part] = ((const float4*)nattr)[(size_t)row * 4 + part];
  }
  if (tid < 2) s_se[tid] = starts[blockIdx.x + tid];
  if (tid == 0) s_bmin = batch[nbase];
  __syncthreads();
  int is = s_se[0], ie = s_se[1];

  int wave = tid >> 6;             // 0..3
  int lane = tid & 63;
  int ep = lane / 10;              // 0..6 (6 -> idle lane)
  int jp = lane - ep * 10;         // 0..9
  bool act = ep < 6;
  int epc = act ? ep : 0;

  v2f bj = {bm[2 * jp], bm[2 * jp + 1]};

  // resident weights: 96 VGPRs, loaded ONCE via LDS bounce, pinned.
  v2f W[48];
#pragma unroll
  for (int t = 0; t < 24; ++t) {
    float4 q = wt4[jp * 25 + t];
    W[2 * t]     = v2f{q.x, q.y};
    W[2 * t + 1] = v2f{q.z, q.w};
  }
#pragma unroll
  for (int k = 0; k < 48; ++k) asm volatile("" : "+v"(W[k]));

  int base = is + wave * 6;
  if (PRE) {
    // ---- streaming path with 1-deep feature prefetch ----
    int sp0 = 0, sp1 = 0, sp2 = 0;
    float4 e0, e1, e2, e3, n0, n1, n2, n3;
    if (base < ie) {
      sp0 = pm[min(base + epc, ie - 1)];
      sp1 = (base + 24 < ie) ? pm[min(base + 24 + epc, ie - 1)] : sp0;
      sp2 = (base + 48 < ie) ? pm[min(base + 48 + epc, ie - 1)] : sp1;
      const float4* pe = (const float4*)eattr + (size_t)min(base + epc, ie - 1) * 4;
      const float4* ps = (const float4*)nattr + (size_t)(sp0 & 0xFFFFFF) * 4;
      e0 = pe[0]; e1 = pe[1]; e2 = pe[2]; e3 = pe[3];
      n0 = ps[0]; n1 = ps[1]; n2 = ps[2]; n3 = ps[3];
    }
    while (base < ie) {
      int sp3 = (base + 72 < ie) ? pm[min(base + 72 + epc, ie - 1)] : sp2;
      // prefetch iter-(i+1) features: eattr affine, nattr addr from sp1
      const float4* peN = (const float4*)eattr + (size_t)min(base + 24 + epc, ie - 1) * 4;
      const float4* psN = (const float4*)nattr + (size_t)(sp1 & 0xFFFFFF) * 4;
      float4 e0N = peN[0], e1N = peN[1], e2N = peN[2], e3N = peN[3];
      float4 n0N = psN[0], n1N = psN[1], n2N = psN[2], n3N = psN[3];

      int dl = (sp0 >> 24) & 63;
      float4 u0 = us4[dl * 5 + 0], u1 = us4[dl * 5 + 1];
      float4 u2 = us4[dl * 5 + 2], u3 = us4[dl * 5 + 3];

      v2f a0 = {0.f, 0.f}, a1 = {0.f, 0.f}, a2 = {0.f, 0.f}, a3 = {0.f, 0.f};
      PK4(n0, 0)  PK4(n1, 4)  PK4(n2, 8)  PK4(n3, 12)     // src feats
      PK4(u0, 16) PK4(u1, 20) PK4(u2, 24) PK4(u3, 28)     // dst feats
      PK4(e0, 32) PK4(e1, 36) PK4(e2, 40) PK4(e3, 44)     // edge feats
      v2f r = ((a0 + a1) + (a2 + a3)) + bj;

      bool valid = act && (base + epc < ie);
      float m0 = fmaxf(r.x, 0.f);
      float m1 = fmaxf(r.y, 0.f);
      if (valid && m0 > 0.f) atomicAdd(&xt[(2 * jp) * 65 + dl], m0);     // LDS
      if (valid && m1 > 0.f) atomicAdd(&xt[(2 * jp + 1) * 65 + dl], m1);

      base += 24; sp0 = sp1; sp1 = sp2; sp2 = sp3;
      e0 = e0N; e1 = e1N; e2 = e2N; e3 = e3N;
      n0 = n0N; n1 = n1N; n2 = n2N; n3 = n3N;
    }
  } else {
    // ---- fallback gather path (R9 structure, no prefetch) ----
    int sp0 = 0, sp1 = 0, sp2 = 0, sv0 = 0;
    if (base < ie) {
      sp0 = pm[min(base + epc, ie - 1)];
      sp1 = (base + 24 < ie) ? pm[min(base + 24 + epc, ie - 1)] : sp0;
      sp2 = (base + 48 < ie) ? pm[min(base + 48 + epc, ie - 1)] : sp1;
      sv0 = ei[sp0 & 0xFFFFFF];
    }
    while (base < ie) {
      int sp3 = (base + 72 < ie) ? pm[min(base + 72 + epc, ie - 1)] : sp2;
      int svN = (base + 24 < ie) ? ei[sp1 & 0xFFFFFF] : sv0;

      const float4* pe = (const float4*)eattr + (size_t)(sp0 & 0xFFFFFF) * 4;
      const float4* ps = (const float4*)nattr + (size_t)sv0 * 4;
      float4 e0 = pe[0], e1 = pe[1], e2 = pe[2], e3 = pe[3];
      float4 n0 = ps[0], n1 = ps[1], n2 = ps[2], n3 = ps[3];
      int dl = (sp0 >> 24) & 63;
      float4 u0 = us4[dl * 5 + 0], u1 = us4[dl * 5 + 1];
      float4 u2 = us4[dl * 5 + 2], u3 = us4[dl * 5 + 3];

      v2f a0 = {0.f, 0.f}, a1 = {0.f, 0.f}, a2 = {0.f, 0.f}, a3 = {0.f, 0.f};
      PK4(n0, 0)  PK4(n1, 4)  PK4(n2, 8)  PK4(n3, 12)
      PK4(u0, 16) PK4(u1, 20) PK4(u2, 24) PK4(u3, 28)
      PK4(e0, 32) PK4(e1, 36) PK4(e2, 40) PK4(e3, 44)
      v2f r = ((a0 + a1) + (a2 + a3)) + bj;

      bool valid = act && (base + epc < ie);
      float m0 = fmaxf(r.x, 0.f);
      float m1 = fmaxf(r.y, 0.f);
      if (valid && m0 > 0.f) atomicAdd(&xt[(2 * jp) * 65 + dl], m0);
      if (valid && m1 > 0.f) atomicAdd(&xt[(2 * jp + 1) * 65 + dl], m1);

      base += 24; sp0 = sp1; sp1 = sp2; sp2 = sp3; sv0 = svN;
    }
  }
  __syncthreads();

  // ---- fused node MLP (20 -> 10, relu) + graph pre-aggregation ----
  int nn = min(BKT, NN - nbase);
  int bmin = s_bmin;
  if (tid < 64 && tid < nn) {
    int node = tid;
    float xi[20];
#pragma unroll
    for (int j = 0; j < 20; ++j) xi[j] = xt[j * 65 + node];
    float acc[10];
#pragma unroll
    for (int j = 0; j < 10; ++j) acc[j] = b1[j];
#pragma unroll
    for (int k = 0; k < 20; ++k) {
      float fk = xi[k];
#pragma unroll
      for (int j = 0; j < 10; ++j) acc[j] = fmaf(fk, W1[k * 10 + j], acc[j]);
    }
    int bn = batch[nbase + node];
    int d = bn - bmin;                                  // >= 0 (batch sorted)
    if (d < 64) {
#pragma unroll
      for (int j = 0; j < 10; ++j) {
        float m = fmaxf(acc[j], 0.f);
        if (m > 0.f) atomicAdd(&gb[d * 10 + j], m);     // LDS
      }
    } else {                                            // rare large jump
#pragma unroll
      for (int j = 0; j < 10; ++j) {
        float m = fmaxf(acc[j], 0.f);
        if (m > 0.f) unsafeAtomicAdd(&g[(size_t)bn * 10 + j], m);
      }
    }
  }
  __syncthreads();
  int glim = min(640, NG * 10 - bmin * 10);
  float* gp = g + (size_t)bmin * 10;
  for (int idx = tid; idx < glim; idx += 256) {
    float v = gb[idx];
    if (v != 0.f) unsafeAtomicAdd(&gp[idx], v);         // ~40 sparse atomics/block
  }
}

// ---------------- graph MLP ----------------
__global__ __launch_bounds__(256) void k_graph(
    const float* __restrict__ g,
    const float* __restrict__ W2, const float* __restrict__ b2,
    const float* __restrict__ W3, const float* __restrict__ b3,
    float* __restrict__ out) {
  int i = blockIdx.x * 256 + threadIdx.x;
  if (i >= NG) return;
  float gi[10];
  const float2* pg = (const float2*)(g + (size_t)i * 10);
#pragma unroll
  for (int k = 0; k < 5; ++k) { float2 v = pg[k]; gi[2*k] = v.x; gi[2*k+1] = v.y; }
  float o = b3[0];
#pragma unroll
  for (int j = 0; j < 10; ++j) {
    float a = b2[j];
#pragma unroll
    for (int k = 0; k < 10; ++k) a = fmaf(gi[k], W2[k * 10 + j], a);
    o = fmaf(fmaxf(a, 0.f), W3[j], o);
  }
  out[i] = o;
}

extern "C" void kernel_launch(void* const* d_in, const int* in_sizes, int n_in,
                              void* d_out, int out_size, void* d_ws, size_t ws_size,
                              hipStream_t stream) {
  const int*   ei    = (const int*)  d_in[0];
  const float* nattr = (const float*)d_in[1];
  const float* eattr = (const float*)d_in[2];
  const int*   batch = (const int*)  d_in[3];
  const float* Wm    = (const float*)d_in[4];
  const float* bm    = (const float*)d_in[5];
  const float* W1    = (const float*)d_in[6];
  const float* b1    = (const float*)d_in[7];
  const float* W2    = (const float*)d_in[8];
  const float* b2    = (const float*)d_in[9];
  const float* W3    = (const float*)d_in[10];
  const float* b3    = (const float*)d_in[11];

  float* g      = (float*)d_ws + OFF_G;
  int*   bh     = (int*)d_ws + OFF_BH;
  int*   starts = (int*)d_ws + OFF_ST;
  int*   pm     = (int*)d_ws + OFF_PM;     // perm (fallback only)
  int*   srcp   = (int*)d_ws + OFF_SP;
  float* ep_    = (float*)d_ws + OFF_EP;

  bool pre = ws_size >= NEED_WORDS * 4;

  constexpr int SCAN_BLKS = (NBKT + 255) / 256;   // 7

  k_hist   <<<NB, 256, 0, stream>>>(ei, bh, g);
  k_btot   <<<SCAN_BLKS, 256, 0, stream>>>(bh, starts);
  k_sscan  <<<1, 1024, 0, stream>>>(starts);
  k_bases  <<<SCAN_BLKS, 256, 0, stream>>>(bh, starts);
  if (pre) {
    k_scatter<true><<<NB, 256, 0, stream>>>(ei, bh, pm, eattr, ep_, srcp);
    k_edge<true><<<NBKT, 256, 0, stream>>>(ei, nattr, ep_, Wm, bm, batch, W1, b1,
                                           srcp, starts, g);
  } else {
    k_scatter<false><<<NB, 256, 0, stream>>>(ei, bh, pm, eattr, ep_, srcp);
    k_edge<false><<<NBKT, 256, 0, stream>>>(ei, nattr, eattr, Wm, bm, batch, W1, b1,
                                            pm, starts, g);
  }
  k_graph  <<<(NG + 255) / 256, 256, 0, stream>>>(g, W2, b2, W3, b3, (float*)d_out);
}

// Round 11
// 403.913 us; speedup vs baseline: 1.2534x; 1.2534x over previous
//
#include <hip/hip_runtime.h>

constexpr int NN = 100000;   // nodes
constexpr int NE = 1600000;  // edges
constexpr int NG = 5000;     // graphs
constexpr int BKT = 64;      // dst-nodes per bucket
constexpr int NBKT = (NN + BKT - 1) / BKT;   // 1563
constexpr int NB = 512;      // hist/scatter blocks (R10 lesson: 128 used HALF the CUs
                             // at 1 block/CU; 512 -> 2 blocks/CU everywhere, 4x TLP)
constexpr int CHUNK = NE / NB;               // 3125 exact

typedef float v2f __attribute__((ext_vector_type(2)));

// ---- workspace layout (4B words) ----
constexpr size_t OFF_G  = 0;                            // g      [NG*10]
constexpr size_t OFF_BH = 50048;                        // bh     [NB][NBKT]
constexpr size_t OFF_ST = OFF_BH + (size_t)NB * NBKT;   // starts [NBKT+1]
constexpr size_t OFF_PM = OFF_ST + NBKT + 1;            // inv (PRE) / perm [NE]
constexpr size_t OFF_SP = OFF_PM + NE;                  // srcp   [NE]
constexpr size_t OFF_EP = ((OFF_SP + NE) + 15) & ~(size_t)15;  // eattr_perm [NE*16]
constexpr size_t NEED_WORDS = OFF_EP + (size_t)NE * 16; // ~118.6 MB
// R10 post-mortem: fusing reorder into scatter put 150MB of scattered writes
// into a 2-waves/CU kernel (VALUBusy 0.33%, occ 5%) -> 190us. Reorder must
// live where TLP is: separate k_reorder, 25000 blocks (R9 structure). k_edge
// keeps R10's 1-deep prefetch (isolated measurement this round).

// ---------------- pass A: per-block bucket histogram (+ zero g) ----------------
__global__ __launch_bounds__(256) void k_hist(const int* __restrict__ ei,
                                              int* __restrict__ bh,
                                              float* __restrict__ g) {
  __shared__ int lh[NBKT];
  for (int i = threadIdx.x; i < NBKT; i += 256) lh[i] = 0;
  __syncthreads();
  const int* dstp = ei + NE;
  int s = blockIdx.x * CHUNK;
  for (int i = s + threadIdx.x; i < s + CHUNK; i += 256)
    atomicAdd(&lh[dstp[i] >> 6], 1);                    // LDS int atomic
  int gid = blockIdx.x * 256 + threadIdx.x;             // zero g: 12,500 float4
  if (gid < 12500) ((float4*)g)[gid] = make_float4(0.f, 0.f, 0.f, 0.f);
  __syncthreads();
  int* out = bh + (size_t)blockIdx.x * NBKT;            // block-major: coalesced
  for (int k = threadIdx.x; k < NBKT; k += 256) out[k] = lh[k];
}

// ---------------- pass B1: per-bucket totals (grid-parallel) ----------------
__global__ __launch_bounds__(256) void k_btot(const int* __restrict__ bh,
                                              int* __restrict__ starts) {
  int k = blockIdx.x * 256 + threadIdx.x;
  if (k >= NBKT) return;
  int tot = 0;
  for (int b = 0; b < NB; b += 4) {                     // coalesced: k-consecutive
    int a0 = bh[(size_t)(b    ) * NBKT + k];
    int a1 = bh[(size_t)(b + 1) * NBKT + k];
    int a2 = bh[(size_t)(b + 2) * NBKT + k];
    int a3 = bh[(size_t)(b + 3) * NBKT + k];
    tot += a0 + a1 + a2 + a3;
  }
  starts[k] = tot;
}

// ---------------- pass B2: exclusive scan of 1563 totals ----------------
__global__ __launch_bounds__(1024) void k_sscan(int* __restrict__ starts) {
  __shared__ int s0[1024], s1[1024];
  int t = threadIdx.x;
  int k0 = 2 * t, k1 = 2 * t + 1;
  int tot0 = (k0 < NBKT) ? starts[k0] : 0;
  int tot1 = (k1 < NBKT) ? starts[k1] : 0;
  int ssum = tot0 + tot1;
  int* cur = s0; int* nxt = s1;
  cur[t] = ssum;
  __syncthreads();
  for (int off = 1; off < 1024; off <<= 1) {            // Hillis-Steele inclusive
    int v = cur[t];
    if (t >= off) v += cur[t - off];
    nxt[t] = v;
    __syncthreads();
    int* tmp = cur; cur = nxt; nxt = tmp;
  }
  int excl = cur[t] - ssum;
  if (k0 < NBKT) starts[k0] = excl;
  if (k1 <= NBKT) starts[k1] = excl + tot0;             // t=781 writes starts[NBKT]=NE
}

// ---------------- pass B3: per-(block,bucket) bases (grid-parallel) ----------------
__global__ __launch_bounds__(256) void k_bases(int* __restrict__ bh,
                                               const int* __restrict__ starts) {
  int k = blockIdx.x * 256 + threadIdx.x;
  if (k >= NBKT) return;
  int run = starts[k];
#pragma unroll 8
  for (int b = 0; b < NB; ++b) {                        // loads pipeline; adds cheap
    size_t idx = (size_t)b * NBKT + k;
    int v = bh[idx];
    bh[idx] = run;
    run += v;
  }
}

// ---------------- pass C: scatter slots ----------------
// PRE: inv[i] = slot | dl<<25 (coalesced write). Fallback: perm[slot] = i|dl<<24.
template <bool PRE>
__global__ __launch_bounds__(256) void k_scatter(const int* __restrict__ ei,
                                                 const int* __restrict__ bh,
                                                 int* __restrict__ pm) {
  __shared__ int base[NBKT];
  __shared__ int cnt[NBKT];
  const int* row = bh + (size_t)blockIdx.x * NBKT;
  for (int k = threadIdx.x; k < NBKT; k += 256) { base[k] = row[k]; cnt[k] = 0; }
  __syncthreads();
  const int* dstp = ei + NE;
  int s = blockIdx.x * CHUNK;
  for (int i = s + threadIdx.x; i < s + CHUNK; i += 256) {
    int d = dstp[i];
    int k = d >> 6;
    int r = atomicAdd(&cnt[k], 1);                      // LDS atomic
    int slot = base[k] + r;
    if (PRE) pm[i] = slot | ((d & 63) << 25);           // inv: coalesced write
    else     pm[slot] = i | ((d & 63) << 24);           // perm: scattered write
  }
}

// ---------------- pass C2: stream eattr -> bucket-ordered copy ----------------
// 25000 blocks of pure TLP (R10 lesson: this work DIES in a low-occupancy
// kernel). Streaming reads, scattered 64B-aligned writes (fire-and-forget).
__global__ __launch_bounds__(256) void k_reorder(const int* __restrict__ ei,
                                                 const float* __restrict__ eattr,
                                                 const int* __restrict__ inv,
                                                 float* __restrict__ ep_,
                                                 int* __restrict__ srcp) {
  int gid = blockIdx.x * 256 + threadIdx.x;
  int e = gid >> 2, part = gid & 3;
  if (e >= NE) return;
  int iv = inv[e];
  int slot = iv & 0x1FFFFFF;                            // 25 bits
  float4 v = ((const float4*)eattr)[(size_t)e * 4 + part];
  ((float4*)ep_)[(size_t)slot * 4 + part] = v;
  if (part == 0) srcp[slot] = ei[e] | ((iv >> 25) << 24);
}

// ---------------- pass D: edge MLP + fused node MLP + graph pooling ----------------
// Lane (ep,jp): ep = edge slot (6/wave), jp = output pair (10). 4 waves/block.
// PRE: eattr_perm/srcp streaming (affine), nattr[src] the single dependent
// hop. 1-deep feature prefetch (R10): no load's consumer in its issue iter.
// ~215 regs under (256,2) cap 256. Weights: 96 pinned regs.
#define PK4(V, K0) \
  a0 = __builtin_elementwise_fma(v2f{(V).x, (V).x}, W[K0+0], a0); \
  a1 = __builtin_elementwise_fma(v2f{(V).y, (V).y}, W[K0+1], a1); \
  a2 = __builtin_elementwise_fma(v2f{(V).z, (V).z}, W[K0+2], a2); \
  a3 = __builtin_elementwise_fma(v2f{(V).w, (V).w}, W[K0+3], a3);

template <bool PRE>
__global__ __launch_bounds__(256, 2) void k_edge(
    const int* __restrict__ ei,
    const float* __restrict__ nattr,
    const float* __restrict__ eattr,        // PRE: eattr_perm ; else raw eattr
    const float* __restrict__ Wm,
    const float* __restrict__ bm,
    const int* __restrict__ batch,
    const float* __restrict__ W1,
    const float* __restrict__ b1,
    const int* __restrict__ pm,             // PRE: srcp ; else perm
    const int* __restrict__ starts,
    float* __restrict__ g) {
  __shared__ float xt[20 * 65];    // padded rows
  __shared__ float gb[64 * 10];    // graph partials for this bucket's span
  __shared__ float4 wt4[250];      // weight bounce: [jp][t] pairs for cols 2jp,2jp+1
  __shared__ float4 us4[64 * 5];   // dst rows, padded stride 5 (4 used)
  __shared__ int s_se[2];
  __shared__ int s_bmin;
  int tid = threadIdx.x;
  for (int i = tid; i < 20 * 65; i += 256) xt[i] = 0.f;
  for (int i = tid; i < 640; i += 256) gb[i] = 0.f;
  if (tid < 240) {
    int j = tid / 24, t = tid - j * 24, k = 2 * t;
    wt4[j * 25 + t] = make_float4(Wm[k * 20 + 2 * j],       Wm[k * 20 + 2 * j + 1],
                                  Wm[(k + 1) * 20 + 2 * j], Wm[(k + 1) * 20 + 2 * j + 1]);
  }
  int nbase = blockIdx.x * BKT;
  {                                // stage the block's 64 dst rows (once)
    int dl = tid >> 2, part = tid & 3;
    int row = min(nbase + dl, NN - 1);
    us4[dl * 5 + part] = ((const float4*)nattr)[(size_t)row * 4 + part];
  }
  if (tid < 2) s_se[tid] = starts[blockIdx.x + tid];
  if (tid == 0) s_bmin = batch[nbase];
  __syncthreads();
  int is = s_se[0], ie = s_se[1];

  int wave = tid >> 6;             // 0..3
  int lane = tid & 63;
  int ep = lane / 10;              // 0..6 (6 -> idle lane)
  int jp = lane - ep * 10;         // 0..9
  bool act = ep < 6;
  int epc = act ? ep : 0;

  v2f bj = {bm[2 * jp], bm[2 * jp + 1]};

  // resident weights: 96 VGPRs, loaded ONCE via LDS bounce, pinned.
  v2f W[48];
#pragma unroll
  for (int t = 0; t < 24; ++t) {
    float4 q = wt4[jp * 25 + t];
    W[2 * t]     = v2f{q.x, q.y};
    W[2 * t + 1] = v2f{q.z, q.w};
  }
#pragma unroll
  for (int k = 0; k < 48; ++k) asm volatile("" : "+v"(W[k]));

  int base = is + wave * 6;
  if (PRE) {
    // ---- streaming path with 1-deep feature prefetch ----
    int sp0 = 0, sp1 = 0, sp2 = 0;
    float4 e0, e1, e2, e3, n0, n1, n2, n3;
    if (base < ie) {
      sp0 = pm[min(base + epc, ie - 1)];
      sp1 = (base + 24 < ie) ? pm[min(base + 24 + epc, ie - 1)] : sp0;
      sp2 = (base + 48 < ie) ? pm[min(base + 48 + epc, ie - 1)] : sp1;
      const float4* pe = (const float4*)eattr + (size_t)min(base + epc, ie - 1) * 4;
      const float4* ps = (const float4*)nattr + (size_t)(sp0 & 0xFFFFFF) * 4;
      e0 = pe[0]; e1 = pe[1]; e2 = pe[2]; e3 = pe[3];
      n0 = ps[0]; n1 = ps[1]; n2 = ps[2]; n3 = ps[3];
    }
    while (base < ie) {
      int sp3 = (base + 72 < ie) ? pm[min(base + 72 + epc, ie - 1)] : sp2;
      // prefetch iter-(i+1) features: eattr affine, nattr addr from sp1
      const float4* peN = (const float4*)eattr + (size_t)min(base + 24 + epc, ie - 1) * 4;
      const float4* psN = (const float4*)nattr + (size_t)(sp1 & 0xFFFFFF) * 4;
      float4 e0N = peN[0], e1N = peN[1], e2N = peN[2], e3N = peN[3];
      float4 n0N = psN[0], n1N = psN[1], n2N = psN[2], n3N = psN[3];

      int dl = (sp0 >> 24) & 63;
      float4 u0 = us4[dl * 5 + 0], u1 = us4[dl * 5 + 1];
      float4 u2 = us4[dl * 5 + 2], u3 = us4[dl * 5 + 3];

      v2f a0 = {0.f, 0.f}, a1 = {0.f, 0.f}, a2 = {0.f, 0.f}, a3 = {0.f, 0.f};
      PK4(n0, 0)  PK4(n1, 4)  PK4(n2, 8)  PK4(n3, 12)     // src feats
      PK4(u0, 16) PK4(u1, 20) PK4(u2, 24) PK4(u3, 28)     // dst feats
      PK4(e0, 32) PK4(e1, 36) PK4(e2, 40) PK4(e3, 44)     // edge feats
      v2f r = ((a0 + a1) + (a2 + a3)) + bj;

      bool valid = act && (base + epc < ie);
      float m0 = fmaxf(r.x, 0.f);
      float m1 = fmaxf(r.y, 0.f);
      if (valid && m0 > 0.f) atomicAdd(&xt[(2 * jp) * 65 + dl], m0);     // LDS
      if (valid && m1 > 0.f) atomicAdd(&xt[(2 * jp + 1) * 65 + dl], m1);

      base += 24; sp0 = sp1; sp1 = sp2; sp2 = sp3;
      e0 = e0N; e1 = e1N; e2 = e2N; e3 = e3N;
      n0 = n0N; n1 = n1N; n2 = n2N; n3 = n3N;
    }
  } else {
    // ---- fallback gather path (R9 structure, no prefetch) ----
    int sp0 = 0, sp1 = 0, sp2 = 0, sv0 = 0;
    if (base < ie) {
      sp0 = pm[min(base + epc, ie - 1)];
      sp1 = (base + 24 < ie) ? pm[min(base + 24 + epc, ie - 1)] : sp0;
      sp2 = (base + 48 < ie) ? pm[min(base + 48 + epc, ie - 1)] : sp1;
      sv0 = ei[sp0 & 0xFFFFFF];
    }
    while (base < ie) {
      int sp3 = (base + 72 < ie) ? pm[min(base + 72 + epc, ie - 1)] : sp2;
      int svN = (base + 24 < ie) ? ei[sp1 & 0xFFFFFF] : sv0;

      const float4* pe = (const float4*)eattr + (size_t)(sp0 & 0xFFFFFF) * 4;
      const float4* ps = (const float4*)nattr + (size_t)sv0 * 4;
      float4 e0 = pe[0], e1 = pe[1], e2 = pe[2], e3 = pe[3];
      float4 n0 = ps[0], n1 = ps[1], n2 = ps[2], n3 = ps[3];
      int dl = (sp0 >> 24) & 63;
      float4 u0 = us4[dl * 5 + 0], u1 = us4[dl * 5 + 1];
      float4 u2 = us4[dl * 5 + 2], u3 = us4[dl * 5 + 3];

      v2f a0 = {0.f, 0.f}, a1 = {0.f, 0.f}, a2 = {0.f, 0.f}, a3 = {0.f, 0.f};
      PK4(n0, 0)  PK4(n1, 4)  PK4(n2, 8)  PK4(n3, 12)
      PK4(u0, 16) PK4(u1, 20) PK4(u2, 24) PK4(u3, 28)
      PK4(e0, 32) PK4(e1, 36) PK4(e2, 40) PK4(e3, 44)
      v2f r = ((a0 + a1) + (a2 + a3)) + bj;

      bool valid = act && (base + epc < ie);
      float m0 = fmaxf(r.x, 0.f);
      float m1 = fmaxf(r.y, 0.f);
      if (valid && m0 > 0.f) atomicAdd(&xt[(2 * jp) * 65 + dl], m0);
      if (valid && m1 > 0.f) atomicAdd(&xt[(2 * jp + 1) * 65 + dl], m1);

      base += 24; sp0 = sp1; sp1 = sp2; sp2 = sp3; sv0 = svN;
    }
  }
  __syncthreads();

  // ---- fused node MLP (20 -> 10, relu) + graph pre-aggregation ----
  int nn = min(BKT, NN - nbase);
  int bmin = s_bmin;
  if (tid < 64 && tid < nn) {
    int node = tid;
    float xi[20];
#pragma unroll
    for (int j = 0; j < 20; ++j) xi[j] = xt[j * 65 + node];
    float acc[10];
#pragma unroll
    for (int j = 0; j < 10; ++j) acc[j] = b1[j];
#pragma unroll
    for (int k = 0; k < 20; ++k) {
      float fk = xi[k];
#pragma unroll
      for (int j = 0; j < 10; ++j) acc[j] = fmaf(fk, W1[k * 10 + j], acc[j]);
    }
    int bn = batch[nbase + node];
    int d = bn - bmin;                                  // >= 0 (batch sorted)
    if (d < 64) {
#pragma unroll
      for (int j = 0; j < 10; ++j) {
        float m = fmaxf(acc[j], 0.f);
        if (m > 0.f) atomicAdd(&gb[d * 10 + j], m);     // LDS
      }
    } else {                                            // rare large jump
#pragma unroll
      for (int j = 0; j < 10; ++j) {
        float m = fmaxf(acc[j], 0.f);
        if (m > 0.f) unsafeAtomicAdd(&g[(size_t)bn * 10 + j], m);
      }
    }
  }
  __syncthreads();
  int glim = min(640, NG * 10 - bmin * 10);
  float* gp = g + (size_t)bmin * 10;
  for (int idx = tid; idx < glim; idx += 256) {
    float v = gb[idx];
    if (v != 0.f) unsafeAtomicAdd(&gp[idx], v);         // ~40 sparse atomics/block
  }
}

// ---------------- graph MLP ----------------
__global__ __launch_bounds__(256) void k_graph(
    const float* __restrict__ g,
    const float* __restrict__ W2, const float* __restrict__ b2,
    const float* __restrict__ W3, const float* __restrict__ b3,
    float* __restrict__ out) {
  int i = blockIdx.x * 256 + threadIdx.x;
  if (i >= NG) return;
  float gi[10];
  const float2* pg = (const float2*)(g + (size_t)i * 10);
#pragma unroll
  for (int k = 0; k < 5; ++k) { float2 v = pg[k]; gi[2*k] = v.x; gi[2*k+1] = v.y; }
  float o = b3[0];
#pragma unroll
  for (int j = 0; j < 10; ++j) {
    float a = b2[j];
#pragma unroll
    for (int k = 0; k < 10; ++k) a = fmaf(gi[k], W2[k * 10 + j], a);
    o = fmaf(fmaxf(a, 0.f), W3[j], o);
  }
  out[i] = o;
}

extern "C" void kernel_launch(void* const* d_in, const int* in_sizes, int n_in,
                              void* d_out, int out_size, void* d_ws, size_t ws_size,
                              hipStream_t stream) {
  const int*   ei    = (const int*)  d_in[0];
  const float* nattr = (const float*)d_in[1];
  const float* eattr = (const float*)d_in[2];
  const int*   batch = (const int*)  d_in[3];
  const float* Wm    = (const float*)d_in[4];
  const float* bm    = (const float*)d_in[5];
  const float* W1    = (const float*)d_in[6];
  const float* b1    = (const float*)d_in[7];
  const float* W2    = (const float*)d_in[8];
  const float* b2    = (const float*)d_in[9];
  const float* W3    = (const float*)d_in[10];
  const float* b3    = (const float*)d_in[11];

  float* g      = (float*)d_ws + OFF_G;
  int*   bh     = (int*)d_ws + OFF_BH;
  int*   starts = (int*)d_ws + OFF_ST;
  int*   pm     = (int*)d_ws + OFF_PM;     // inv (PRE) / perm (fallback)
  int*   srcp   = (int*)d_ws + OFF_SP;
  float* ep_    = (float*)d_ws + OFF_EP;

  bool pre = ws_size >= NEED_WORDS * 4;

  constexpr int SCAN_BLKS = (NBKT + 255) / 256;   // 7

  k_hist   <<<NB, 256, 0, stream>>>(ei, bh, g);
  k_btot   <<<SCAN_BLKS, 256, 0, stream>>>(bh, starts);
  k_sscan  <<<1, 1024, 0, stream>>>(starts);
  k_bases  <<<SCAN_BLKS, 256, 0, stream>>>(bh, starts);
  if (pre) {
    k_scatter<true><<<NB, 256, 0, stream>>>(ei, bh, pm);
    k_reorder<<<(NE * 4 + 255) / 256, 256, 0, stream>>>(ei, eattr, pm, ep_, srcp);
    k_edge<true><<<NBKT, 256, 0, stream>>>(ei, nattr, ep_, Wm, bm, batch, W1, b1,
                                           srcp, starts, g);
  } else {
    k_scatter<false><<<NB, 256, 0, stream>>>(ei, bh, pm);
    k_edge<false><<<NBKT, 256, 0, stream>>>(ei, nattr, eattr, Wm, bm, batch, W1, b1,
                                            pm, starts, g);
  }
  k_graph  <<<(NG + 255) / 256, 256, 0, stream>>>(g, W2, b2, W3, b3, (float*)d_out);
}

// Round 12
// 379.045 us; speedup vs baseline: 1.3357x; 1.0656x over previous
//
#include <hip/hip_runtime.h>

constexpr int NN = 100000;   // nodes
constexpr int NE = 1600000;  // edges
constexpr int NG = 5000;     // graphs
constexpr int BKT = 64;      // dst-nodes per bucket
constexpr int NBKT = (NN + BKT - 1) / BKT;   // 1563
constexpr int NB = 512;      // hist/scatter blocks (2 blocks/CU)
constexpr int CHUNK = NE / NB;               // 3125 exact

typedef float v2f __attribute__((ext_vector_type(2)));

// ---- workspace layout (4B words) ----
constexpr size_t OFF_G  = 0;                            // g      [NG*10]
constexpr size_t OFF_BH = 50048;                        // bh     [NB][NBKT]
constexpr size_t OFF_ST = OFF_BH + (size_t)NB * NBKT;   // starts [NBKT+1]
constexpr size_t OFF_PM = OFF_ST + NBKT + 1;            // inv (PRE) / perm [NE]
constexpr size_t OFF_SP = OFF_PM + NE;                  // srcp   [NE]
constexpr size_t OFF_EP = ((OFF_SP + NE) + 15) & ~(size_t)15;  // eattr_perm [NE*16]
constexpr size_t NEED_WORDS = OFF_EP + (size_t)NE * 16; // ~118.6 MB (fits, R11 ran PRE)
// R11 post-mortem: (1) explicit 1-deep feature prefetch REGRESSED k_edge
// 134.8->154 (compiler already pipelines the R9 body; hand-held float4 state
// hurts every time: R2 spill, R11 sched) -> reverted. (2) rest ~250us is
// NB-invariant -> not hist/scatter occupancy.
// R12 lever: linearity. msg = relu(n@Ws + u@Wd + e@We + b); the u@Wd+b term
// only has 64 values per bucket -> precompute pd[64][20] in the prologue
// (LDS), drop Wd from the loop: 64 pinned W regs (was 96), 32 FMA-steps
// (was 48), 1 ds_read_b64 (was 4 b128). ~148-164 total regs <= 170 cap from
// (256,3) -> 3 waves/SIMD (was 2): the occupancy unlock R9 couldn't reach.

// ---------------- pass A: per-block bucket histogram (+ zero g) ----------------
__global__ __launch_bounds__(256) void k_hist(const int* __restrict__ ei,
                                              int* __restrict__ bh,
                                              float* __restrict__ g) {
  __shared__ int lh[NBKT];
  for (int i = threadIdx.x; i < NBKT; i += 256) lh[i] = 0;
  __syncthreads();
  const int* dstp = ei + NE;
  int s = blockIdx.x * CHUNK;
  for (int i = s + threadIdx.x; i < s + CHUNK; i += 256)
    atomicAdd(&lh[dstp[i] >> 6], 1);                    // LDS int atomic
  int gid = blockIdx.x * 256 + threadIdx.x;             // zero g: 12,500 float4
  if (gid < 12500) ((float4*)g)[gid] = make_float4(0.f, 0.f, 0.f, 0.f);
  __syncthreads();
  int* out = bh + (size_t)blockIdx.x * NBKT;            // block-major: coalesced
  for (int k = threadIdx.x; k < NBKT; k += 256) out[k] = lh[k];
}

// ---------------- pass B1: per-bucket totals (grid-parallel) ----------------
__global__ __launch_bounds__(256) void k_btot(const int* __restrict__ bh,
                                              int* __restrict__ starts) {
  int k = blockIdx.x * 256 + threadIdx.x;
  if (k >= NBKT) return;
  int tot = 0;
  for (int b = 0; b < NB; b += 4) {                     // coalesced: k-consecutive
    int a0 = bh[(size_t)(b    ) * NBKT + k];
    int a1 = bh[(size_t)(b + 1) * NBKT + k];
    int a2 = bh[(size_t)(b + 2) * NBKT + k];
    int a3 = bh[(size_t)(b + 3) * NBKT + k];
    tot += a0 + a1 + a2 + a3;
  }
  starts[k] = tot;
}

// ---------------- pass B2: exclusive scan of 1563 totals ----------------
__global__ __launch_bounds__(1024) void k_sscan(int* __restrict__ starts) {
  __shared__ int s0[1024], s1[1024];
  int t = threadIdx.x;
  int k0 = 2 * t, k1 = 2 * t + 1;
  int tot0 = (k0 < NBKT) ? starts[k0] : 0;
  int tot1 = (k1 < NBKT) ? starts[k1] : 0;
  int ssum = tot0 + tot1;
  int* cur = s0; int* nxt = s1;
  cur[t] = ssum;
  __syncthreads();
  for (int off = 1; off < 1024; off <<= 1) {            // Hillis-Steele inclusive
    int v = cur[t];
    if (t >= off) v += cur[t - off];
    nxt[t] = v;
    __syncthreads();
    int* tmp = cur; cur = nxt; nxt = tmp;
  }
  int excl = cur[t] - ssum;
  if (k0 < NBKT) starts[k0] = excl;
  if (k1 <= NBKT) starts[k1] = excl + tot0;             // t=781 writes starts[NBKT]=NE
}

// ---------------- pass B3: per-(block,bucket) bases (grid-parallel) ----------------
__global__ __launch_bounds__(256) void k_bases(int* __restrict__ bh,
                                               const int* __restrict__ starts) {
  int k = blockIdx.x * 256 + threadIdx.x;
  if (k >= NBKT) return;
  int run = starts[k];
#pragma unroll 8
  for (int b = 0; b < NB; ++b) {                        // loads pipeline; adds cheap
    size_t idx = (size_t)b * NBKT + k;
    int v = bh[idx];
    bh[idx] = run;
    run += v;
  }
}

// ---------------- pass C: scatter slots ----------------
// PRE: inv[i] = slot | dl<<25 (coalesced write). Fallback: perm[slot] = i|dl<<24.
template <bool PRE>
__global__ __launch_bounds__(256) void k_scatter(const int* __restrict__ ei,
                                                 const int* __restrict__ bh,
                                                 int* __restrict__ pm) {
  __shared__ int base[NBKT];
  __shared__ int cnt[NBKT];
  const int* row = bh + (size_t)blockIdx.x * NBKT;
  for (int k = threadIdx.x; k < NBKT; k += 256) { base[k] = row[k]; cnt[k] = 0; }
  __syncthreads();
  const int* dstp = ei + NE;
  int s = blockIdx.x * CHUNK;
  for (int i = s + threadIdx.x; i < s + CHUNK; i += 256) {
    int d = dstp[i];
    int k = d >> 6;
    int r = atomicAdd(&cnt[k], 1);                      // LDS atomic
    int slot = base[k] + r;
    if (PRE) pm[i] = slot | ((d & 63) << 25);           // inv: coalesced write
    else     pm[slot] = i | ((d & 63) << 24);           // perm: scattered write
  }
}

// ---------------- pass C2: stream eattr -> bucket-ordered copy ----------------
// 25000 blocks of pure TLP. Streaming reads, scattered 64B writes.
__global__ __launch_bounds__(256) void k_reorder(const int* __restrict__ ei,
                                                 const float* __restrict__ eattr,
                                                 const int* __restrict__ inv,
                                                 float* __restrict__ ep_,
                                                 int* __restrict__ srcp) {
  int gid = blockIdx.x * 256 + threadIdx.x;
  int e = gid >> 2, part = gid & 3;
  if (e >= NE) return;
  int iv = inv[e];
  int slot = iv & 0x1FFFFFF;                            // 25 bits
  float4 v = ((const float4*)eattr)[(size_t)e * 4 + part];
  ((float4*)ep_)[(size_t)slot * 4 + part] = v;
  if (part == 0) srcp[slot] = ei[e] | ((iv >> 25) << 24);
}

// ---------------- pass D: edge MLP + fused node MLP + graph pooling ----------------
// Lane (ep,jp): ep = edge slot (6/wave), jp = output pair (10). 4 waves/block.
// pd[64][10] v2f in LDS = dst-contribution + bias precomputed per bucket node
// (linearity). In-loop: 8 affine/1-hop global float4 loads, 1 ds_read_b64,
// 32 pk-FMA steps, 2 LDS atomics. W_src+W_edge = 64 pinned regs.
#define PK4(V, K0) \
  a0 = __builtin_elementwise_fma(v2f{(V).x, (V).x}, W[K0+0], a0); \
  a1 = __builtin_elementwise_fma(v2f{(V).y, (V).y}, W[K0+1], a1); \
  a2 = __builtin_elementwise_fma(v2f{(V).z, (V).z}, W[K0+2], a2); \
  a3 = __builtin_elementwise_fma(v2f{(V).w, (V).w}, W[K0+3], a3);

template <bool PRE>
__global__ __launch_bounds__(256, 3) void k_edge(
    const int* __restrict__ ei,
    const float* __restrict__ nattr,
    const float* __restrict__ eattr,        // PRE: eattr_perm ; else raw eattr
    const float* __restrict__ Wm,
    const float* __restrict__ bm,
    const int* __restrict__ batch,
    const float* __restrict__ W1,
    const float* __restrict__ b1,
    const int* __restrict__ pm,             // PRE: srcp ; else perm
    const int* __restrict__ starts,
    float* __restrict__ g) {
  __shared__ float xt[20 * 65];    // padded rows
  __shared__ float gb[64 * 10];    // graph partials for this bucket's span
  __shared__ float4 wt4[250];      // weight bounce: [jp][t] t=0..23 pairs (2t,2t+1)
  __shared__ float4 us4[64 * 5];   // dst rows, padded stride 5 (prologue use only)
  __shared__ v2f pd2[64 * 11];     // pd[node][jp] = u@Wd pair + bias, stride 11
  __shared__ int s_se[2];
  __shared__ int s_bmin;
  int tid = threadIdx.x;
  for (int i = tid; i < 20 * 65; i += 256) xt[i] = 0.f;
  for (int i = tid; i < 640; i += 256) gb[i] = 0.f;
  if (tid < 240) {
    int j = tid / 24, t = tid - j * 24, k = 2 * t;
    wt4[j * 25 + t] = make_float4(Wm[k * 20 + 2 * j],       Wm[k * 20 + 2 * j + 1],
                                  Wm[(k + 1) * 20 + 2 * j], Wm[(k + 1) * 20 + 2 * j + 1]);
  }
  int nbase = blockIdx.x * BKT;
  {                                // stage the block's 64 dst rows (once)
    int dl = tid >> 2, part = tid & 3;
    int row = min(nbase + dl, NN - 1);
    us4[dl * 5 + part] = ((const float4*)nattr)[(size_t)row * 4 + part];
  }
  if (tid < 2) s_se[tid] = starts[blockIdx.x + tid];
  if (tid == 0) s_bmin = batch[nbase];
  __syncthreads();
  int is = s_se[0], ie = s_se[1];

  int wave = tid >> 6;             // 0..3
  int lane = tid & 63;
  int ep = lane / 10;              // 0..6 (6 -> idle lane)
  int jp = lane - ep * 10;         // 0..9
  bool act = ep < 6;
  int epc = act ? ep : 0;

  // resident weights: W[0..15]=src (k 0..15), W[16..31]=edge (k 32..47).
  // 64 VGPRs, loaded ONCE via LDS bounce, pinned.
  v2f W[32];
#pragma unroll
  for (int t = 0; t < 8; ++t) {
    float4 q = wt4[jp * 25 + t];
    W[2 * t]     = v2f{q.x, q.y};
    W[2 * t + 1] = v2f{q.z, q.w};
  }
#pragma unroll
  for (int t = 16; t < 24; ++t) {
    float4 q = wt4[jp * 25 + t];
    W[2 * (t - 8)]     = v2f{q.x, q.y};
    W[2 * (t - 8) + 1] = v2f{q.z, q.w};
  }
#pragma unroll
  for (int k = 0; k < 32; ++k) asm volatile("" : "+v"(W[k]));

  // pd2[node][jp] = sum_k u_k * Wd[k][2jp..2jp+1] + bias pair (t = 8..15)
  for (int idx = tid; idx < 640; idx += 256) {
    int node = idx / 10, jj = idx - node * 10;
    const float* uf = (const float*)&us4[node * 5];
    v2f acc = {bm[2 * jj], bm[2 * jj + 1]};
#pragma unroll
    for (int m = 0; m < 8; ++m) {
      float4 q = wt4[jj * 25 + 8 + m];
      float ua = uf[2 * m], ub = uf[2 * m + 1];
      acc = __builtin_elementwise_fma(v2f{ua, ua}, v2f{q.x, q.y}, acc);
      acc = __builtin_elementwise_fma(v2f{ub, ub}, v2f{q.z, q.w}, acc);
    }
    pd2[node * 11 + jj] = acc;
  }
  __syncthreads();

  // R9 loop body (no float4 prefetch - compiler pipelines it better than we
  // do: R11 measured hand-prefetch at +20us). srcp/perm pipeline 3-deep ints.
  int base = is + wave * 6;
  int sp0 = 0, sp1 = 0, sp2 = 0, sv0 = 0;
  if (base < ie) {
    sp0 = pm[min(base + epc, ie - 1)];
    sp1 = (base + 24 < ie) ? pm[min(base + 24 + epc, ie - 1)] : sp0;
    sp2 = (base + 48 < ie) ? pm[min(base + 48 + epc, ie - 1)] : sp1;
    if (!PRE) sv0 = ei[sp0 & 0xFFFFFF];
  }
  while (base < ie) {
    int sp3 = (base + 72 < ie) ? pm[min(base + 72 + epc, ie - 1)] : sp2;
    int svN = 0;
    if (!PRE) svN = (base + 24 < ie) ? ei[sp1 & 0xFFFFFF] : sv0;

    size_t eidx = PRE ? (size_t)min(base + epc, ie - 1)
                      : (size_t)(sp0 & 0xFFFFFF);
    int src = PRE ? (sp0 & 0xFFFFFF) : sv0;
    const float4* pe = (const float4*)eattr + eidx * 4;
    const float4* ps = (const float4*)nattr + (size_t)src * 4;
    float4 e0 = pe[0], e1 = pe[1], e2 = pe[2], e3 = pe[3];
    float4 n0 = ps[0], n1 = ps[1], n2 = ps[2], n3 = ps[3];
    int dl = (sp0 >> 24) & 63;
    v2f pdv = pd2[dl * 11 + jp];

    v2f a0 = {0.f, 0.f}, a1 = {0.f, 0.f}, a2 = {0.f, 0.f}, a3 = {0.f, 0.f};
    PK4(n0, 0)  PK4(n1, 4)  PK4(n2, 8)  PK4(n3, 12)     // src feats  (k 0..15)
    PK4(e0, 16) PK4(e1, 20) PK4(e2, 24) PK4(e3, 28)     // edge feats (k 32..47)
    v2f r = ((a0 + a1) + (a2 + a3)) + pdv;

    bool valid = act && (base + epc < ie);
    float m0 = fmaxf(r.x, 0.f);
    float m1 = fmaxf(r.y, 0.f);
    if (valid && m0 > 0.f) atomicAdd(&xt[(2 * jp) * 65 + dl], m0);     // LDS
    if (valid && m1 > 0.f) atomicAdd(&xt[(2 * jp + 1) * 65 + dl], m1);

    base += 24; sp0 = sp1; sp1 = sp2; sp2 = sp3; sv0 = svN;
  }
  __syncthreads();

  // ---- fused node MLP (20 -> 10, relu) + graph pre-aggregation ----
  int nn = min(BKT, NN - nbase);
  int bmin = s_bmin;
  if (tid < 64 && tid < nn) {
    int node = tid;
    float xi[20];
#pragma unroll
    for (int j = 0; j < 20; ++j) xi[j] = xt[j * 65 + node];
    float acc[10];
#pragma unroll
    for (int j = 0; j < 10; ++j) acc[j] = b1[j];
#pragma unroll
    for (int k = 0; k < 20; ++k) {
      float fk = xi[k];
#pragma unroll
      for (int j = 0; j < 10; ++j) acc[j] = fmaf(fk, W1[k * 10 + j], acc[j]);
    }
    int bn = batch[nbase + node];
    int d = bn - bmin;                                  // >= 0 (batch sorted)
    if (d < 64) {
#pragma unroll
      for (int j = 0; j < 10; ++j) {
        float m = fmaxf(acc[j], 0.f);
        if (m > 0.f) atomicAdd(&gb[d * 10 + j], m);     // LDS
      }
    } else {                                            // rare large jump
#pragma unroll
      for (int j = 0; j < 10; ++j) {
        float m = fmaxf(acc[j], 0.f);
        if (m > 0.f) unsafeAtomicAdd(&g[(size_t)bn * 10 + j], m);
      }
    }
  }
  __syncthreads();
  int glim = min(640, NG * 10 - bmin * 10);
  float* gp = g + (size_t)bmin * 10;
  for (int idx = tid; idx < glim; idx += 256) {
    float v = gb[idx];
    if (v != 0.f) unsafeAtomicAdd(&gp[idx], v);         // ~40 sparse atomics/block
  }
}

// ---------------- graph MLP ----------------
__global__ __launch_bounds__(256) void k_graph(
    const float* __restrict__ g,
    const float* __restrict__ W2, const float* __restrict__ b2,
    const float* __restrict__ W3, const float* __restrict__ b3,
    float* __restrict__ out) {
  int i = blockIdx.x * 256 + threadIdx.x;
  if (i >= NG) return;
  float gi[10];
  const float2* pg = (const float2*)(g + (size_t)i * 10);
#pragma unroll
  for (int k = 0; k < 5; ++k) { float2 v = pg[k]; gi[2*k] = v.x; gi[2*k+1] = v.y; }
  float o = b3[0];
#pragma unroll
  for (int j = 0; j < 10; ++j) {
    float a = b2[j];
#pragma unroll
    for (int k = 0; k < 10; ++k) a = fmaf(gi[k], W2[k * 10 + j], a);
    o = fmaf(fmaxf(a, 0.f), W3[j], o);
  }
  out[i] = o;
}

extern "C" void kernel_launch(void* const* d_in, const int* in_sizes, int n_in,
                              void* d_out, int out_size, void* d_ws, size_t ws_size,
                              hipStream_t stream) {
  const int*   ei    = (const int*)  d_in[0];
  const float* nattr = (const float*)d_in[1];
  const float* eattr = (const float*)d_in[2];
  const int*   batch = (const int*)  d_in[3];
  const float* Wm    = (const float*)d_in[4];
  const float* bm    = (const float*)d_in[5];
  const float* W1    = (const float*)d_in[6];
  const float* b1    = (const float*)d_in[7];
  const float* W2    = (const float*)d_in[8];
  const float* b2    = (const float*)d_in[9];
  const float* W3    = (const float*)d_in[10];
  const float* b3    = (const float*)d_in[11];

  float* g      = (float*)d_ws + OFF_G;
  int*   bh     = (int*)d_ws + OFF_BH;
  int*   starts = (int*)d_ws + OFF_ST;
  int*   pm     = (int*)d_ws + OFF_PM;     // inv (PRE) / perm (fallback)
  int*   srcp   = (int*)d_ws + OFF_SP;
  float* ep_    = (float*)d_ws + OFF_EP;

  bool pre = ws_size >= NEED_WORDS * 4;

  constexpr int SCAN_BLKS = (NBKT + 255) / 256;   // 7

  k_hist   <<<NB, 256, 0, stream>>>(ei, bh, g);
  k_btot   <<<SCAN_BLKS, 256, 0, stream>>>(bh, starts);
  k_sscan  <<<1, 1024, 0, stream>>>(starts);
  k_bases  <<<SCAN_BLKS, 256, 0, stream>>>(bh, starts);
  if (pre) {
    k_scatter<true><<<NB, 256, 0, stream>>>(ei, bh, pm);
    k_reorder<<<(NE * 4 + 255) / 256, 256, 0, stream>>>(ei, eattr, pm, ep_, srcp);
    k_edge<true><<<NBKT, 256, 0, stream>>>(ei, nattr, ep_, Wm, bm, batch, W1, b1,
                                           srcp, starts, g);
  } else {
    k_scatter<false><<<NB, 256, 0, stream>>>(ei, bh, pm);
    k_edge<false><<<NBKT, 256, 0, stream>>>(ei, nattr, eattr, Wm, bm, batch, W1, b1,
                                            pm, starts, g);
  }
  k_graph  <<<(NG + 255) / 256, 256, 0, stream>>>(g, W2, b2, W3, b3, (float*)d_out);
}